// Round 11
// baseline (416.992 us; speedup 1.0000x reference)
//
#include <hip/hip_runtime.h>
#include <hip/hip_bf16.h>
#include <stdint.h>

#define BB 64
#define DD 2048
#define VV 50257
#define NB 4096      // histogram bins
#define MAXC 2048    // boundary-bin collect capacity

struct U2 { unsigned x, y; };

__device__ __forceinline__ unsigned rotl32(unsigned v, int r) {
  return (v << r) | (v >> (32 - r));
}

// JAX threefry2x32 (jax/_src/prng.py lowering), 20 rounds.
__device__ __forceinline__ U2 threefry2x32(unsigned k0, unsigned k1,
                                           unsigned x0, unsigned x1) {
  unsigned k2 = k0 ^ k1 ^ 0x1BD11BDAu;
  x0 += k0; x1 += k1;
#define TF_R4(r1, r2, r3, r4)                         \
  x0 += x1; x1 = rotl32(x1, r1); x1 ^= x0;            \
  x0 += x1; x1 = rotl32(x1, r2); x1 ^= x0;            \
  x0 += x1; x1 = rotl32(x1, r3); x1 ^= x0;            \
  x0 += x1; x1 = rotl32(x1, r4); x1 ^= x0;
  TF_R4(13, 15, 26, 6)   x0 += k1; x1 += k2 + 1u;
  TF_R4(17, 29, 16, 24)  x0 += k2; x1 += k0 + 2u;
  TF_R4(13, 15, 26, 6)   x0 += k0; x1 += k1 + 3u;
  TF_R4(17, 29, 16, 24)  x0 += k1; x1 += k2 + 4u;
  TF_R4(13, 15, 26, 6)   x0 += k2; x1 += k0 + 5u;
#undef TF_R4
  U2 r; r.x = x0; r.y = x1; return r;
}

// VALIDATED (R5): partitionable threefry bits = XOR-fold of both cipher words,
// counter (hi=0, lo=e), key (0, 42).
__device__ __forceinline__ unsigned jax_random_bits(unsigned e) {
  U2 r = threefry2x32(0u, 42u, 0u, e);
  return r.x ^ r.y;
}

__device__ __forceinline__ unsigned mono_key(float zi) {
  unsigned bb = __float_as_uint(zi);
  return bb ^ ((bb >> 31) ? 0xFFFFFFFFu : 0x80000000u);
}

// xT[d][b] = x[b][d]: GEMM stages contiguous [d][b] slices into LDS.
__global__ __launch_bounds__(256) void transpose_kernel(
    const float* __restrict__ x, float* __restrict__ xT) {
  int i = blockIdx.x * 256 + threadIdx.x;
  if (i < BB * DD) {
    int b = i >> 11;
    int d = i & 2047;
    xT[d * BB + b] = x[i];
  }
}

// Split-K GEMM, kc=128 only. R6 inner loop byte-identical EXCEPT x comes from
// LDS instead of global/SMEM. Rationale (R10 falsification): x via s_load
// forces full lgkmcnt(0) drains (SMEM is out-of-order) -> per-wave serial
// [load, drain ~250cyc, 128cyc FMA] -> 40% VALU ceiling REGARDLESS of
// occupancy. DS reads are in-order (fine-grained lgkmcnt, m97) and uniform-
// address LDS broadcasts are conflict-free (m136), ~4cyc/b128 -> 16 reads
// = 64 cyc << 128 cyc FMA per d-step -> VALU-bound.
__global__ __launch_bounds__(256, 1) void gemm_splitk_lds_kernel(
    const float* __restrict__ xT, const float* __restrict__ W,
    float* __restrict__ partial) {
  __shared__ float lx[128 * BB];               // 32 KB x-slice
  const int tid = threadIdx.x;
  const int v = blockIdx.x * 256 + tid;
  const int vc = (v < VV) ? v : (VV - 1);
  const int d0 = blockIdx.y * 128;
  {
    const float4* gx = (const float4*)(xT + (size_t)d0 * BB);
#pragma unroll
    for (int q = 0; q < 8; ++q)               // 2048 float4 / 256 thr
      ((float4*)lx)[q * 256 + tid] = gx[q * 256 + tid];
  }
  __syncthreads();

  float acc[BB];
#pragma unroll
  for (int b = 0; b < BB; ++b) acc[b] = 0.0f;
  const float* wp = W + (size_t)d0 * VV + vc;
#pragma unroll 2
  for (int d = 0; d < 128; ++d) {
    const float w = wp[(size_t)d * VV];
    const float* xv = lx + d * BB;             // wave-uniform LDS broadcast
#pragma unroll
    for (int b = 0; b < BB; ++b) acc[b] = fmaf(xv[b], w, acc[b]);
  }
  if (v < VV) {
    float* pp = partial + (size_t)blockIdx.y * BB * VV + v;
#pragma unroll
    for (int b = 0; b < BB; ++b) pp[(size_t)b * VV] = acc[b];
  }
}

// R6-exact split-K (x via SMEM) — fallback for sk<16.
__global__ __launch_bounds__(256, 1) void gemm_splitk_kernel(
    const float* __restrict__ xT, const float* __restrict__ W,
    float* __restrict__ partial, int kc) {
  const int v = blockIdx.x * 256 + threadIdx.x;
  const int vc = (v < VV) ? v : (VV - 1);
  const int d0 = blockIdx.y * kc;
  float acc[BB];
#pragma unroll
  for (int b = 0; b < BB; ++b) acc[b] = 0.0f;
  const float* wp = W + (size_t)d0 * VV + vc;
  const float* xr = xT + d0 * BB;
#pragma unroll 2
  for (int d = 0; d < kc; ++d) {
    const float w = wp[(size_t)d * VV];
    const float* xv = xr + d * BB;
#pragma unroll
    for (int b = 0; b < BB; ++b) acc[b] = fmaf(xv[b], w, acc[b]);
  }
  if (v < VV) {
    float* pp = partial + (size_t)blockIdx.y * BB * VV + v;
#pragma unroll
    for (int b = 0; b < BB; ++b) pp[(size_t)b * VV] = acc[b];
  }
}

// float4 flat reduce: partial planes are [s][flat], flat-contiguous.
__global__ __launch_bounds__(256) void reduce_bias_kernel(
    const float* __restrict__ partial, const float* __restrict__ bias,
    float* __restrict__ logits, int sk) {
  const size_t tot4 = (size_t)BB * VV / 4;   // 3216448 / 4 = 804112
  size_t i = (size_t)blockIdx.x * 256 + threadIdx.x;
  if (i >= tot4) return;
  float4 acc;
  {
    size_t f = i * 4;
    int v0 = (int)(f % VV);
    acc.x = bias[v0];
    acc.y = bias[(v0 + 1 == VV) ? 0 : v0 + 1];
    acc.z = bias[(v0 + 1 >= VV) ? (v0 + 2 - VV) : v0 + 2];
    acc.w = bias[(v0 + 2 >= VV) ? (v0 + 3 - VV) : v0 + 3];
  }
  for (int s = 0; s < sk; ++s) {
    float4 p = ((const float4*)(partial + (size_t)s * BB * VV))[i];
    acc.x += p.x; acc.y += p.y; acc.z += p.z; acc.w += p.w;
  }
  ((float4*)logits)[i] = acc;
}

// Legacy fused GEMM (validated R5) — fallback if ws too small for split-K.
__global__ __launch_bounds__(256, 1) void gemm_kernel(
    const float* __restrict__ xT, const float* __restrict__ W,
    const float* __restrict__ bias, float* __restrict__ logits) {
  const int v = blockIdx.x * 256 + threadIdx.x;
  const int vc = (v < VV) ? v : (VV - 1);
  float acc[BB];
#pragma unroll
  for (int b = 0; b < BB; ++b) acc[b] = 0.0f;
  const float* wp = W + vc;
#pragma unroll 2
  for (int d = 0; d < DD; ++d) {
    const float w = wp[(size_t)d * VV];
    const float* xr = xT + d * BB;
#pragma unroll
    for (int b = 0; b < BB; ++b) acc[b] = fmaf(xr[b], w, acc[b]);
  }
  if (v < VV) {
    const float bv = bias[v];
#pragma unroll
    for (int b = 0; b < BB; ++b) logits[(size_t)b * VV + v] = acc[b] + bv;
  }
}

// Per row: max -> histogram of w=expf(z-m) binned by (m-z)*256 -> scan to find
// boundary bin (S_above <= C < S_above+bin) -> exact prefix sums within bin
// ((key desc, idx asc) order, same semantics as R5's validated binary search)
// -> t* = min kept key -> gumbel argmax over key >= t*. 4 logits passes vs 35.
__global__ __launch_bounds__(1024) void nucleus_sample_kernel(
    const float* __restrict__ logits, int* __restrict__ out) {
  __shared__ double sd[1024];
  __shared__ float sf[1024];
  __shared__ unsigned su[1024];
  __shared__ int si[1024];
  __shared__ double bins[NB];
  __shared__ int cidx[MAXC];
  __shared__ unsigned ckey[MAXC];
  __shared__ double cw[MAXC];
  __shared__ int ccount;
  __shared__ int sh_chunk;
  __shared__ int sh_bstar;
  __shared__ double sh_sabove;

  const int row = blockIdx.x;
  const int tid = threadIdx.x;
  const float* z = logits + (size_t)row * VV;

  for (int i = tid; i < NB; i += 1024) bins[i] = 0.0;
  if (tid == 0) { ccount = 0; sh_chunk = -1; sh_bstar = -1; }
  __syncthreads();

  // pass 1: row max
  float mx = -3.4e38f;
  for (int i = tid; i < VV; i += 1024) mx = fmaxf(mx, z[i]);
  sf[tid] = mx; __syncthreads();
  for (int s = 512; s > 0; s >>= 1) {
    if (tid < s) sf[tid] = fmaxf(sf[tid], sf[tid + s]);
    __syncthreads();
  }
  const float m = sf[0];
  __syncthreads();

  // pass 2: histogram
  for (int i = tid; i < VV; i += 1024) {
    float zi = z[i];
    int bin = (int)((m - zi) * 256.0f);
    bin = (bin < 0) ? 0 : ((bin > NB - 1) ? NB - 1 : bin);
    atomicAdd(&bins[bin], (double)expf(zi - m));
  }
  __syncthreads();

  // inclusive scan over 1024 chunk-sums (4 bins/chunk), f64
  {
    double c = bins[4 * tid] + bins[4 * tid + 1] + bins[4 * tid + 2] + bins[4 * tid + 3];
    sd[tid] = c; __syncthreads();
    for (int off = 1; off < 1024; off <<= 1) {
      double vv = (tid >= off) ? sd[tid - off] : 0.0;
      __syncthreads();
      sd[tid] += vv;
      __syncthreads();
    }
  }
  const double Z = sd[1023];
  const double C = (double)0.9f * Z;

  if (sd[tid] > C && (tid == 0 || sd[tid - 1] <= C)) sh_chunk = tid;
  __syncthreads();
  if (tid == 0) {
    int tc = sh_chunk;
    if (tc >= 0) {
      double run = (tc > 0) ? sd[tc - 1] : 0.0;
      for (int k = 0; k < 4; ++k) {
        double bw = bins[4 * tc + k];
        if (run + bw > C) { sh_bstar = 4 * tc + k; sh_sabove = run; break; }
        run += bw;
      }
    }
  }
  __syncthreads();
  const int bstar = sh_bstar;
  unsigned tkey = 0u;

  if (bstar >= 0) {
    const double Sab = sh_sabove;
    // pass 3: collect boundary-bin elements
    for (int i = tid; i < VV; i += 1024) {
      float zi = z[i];
      int bin = (int)((m - zi) * 256.0f);
      bin = (bin < 0) ? 0 : ((bin > NB - 1) ? NB - 1 : bin);
      if (bin == bstar) {
        int slot = atomicAdd(&ccount, 1);
        if (slot < MAXC) {
          ckey[slot] = mono_key(zi);
          cidx[slot] = i;
          cw[slot] = (double)expf(zi - m);
        }
      }
    }
    __syncthreads();
    int n = ccount; if (n > MAXC) n = MAXC;
    // kept iff exclusive prefix (in (key desc, idx asc) order) <= C
    unsigned mk = 0xFFFFFFFFu;
    for (int i = tid; i < n; i += 1024) {
      unsigned ki = ckey[i]; int ii = cidx[i];
      double T = Sab;
      for (int j = 0; j < n; ++j) {
        unsigned kj = ckey[j];
        if (kj > ki || (kj == ki && cidx[j] < ii)) T += cw[j];
      }
      if (T <= C) mk = (ki < mk) ? ki : mk;
    }
    su[tid] = mk; __syncthreads();
    for (int s = 512; s > 0; s >>= 1) {
      if (tid < s) su[tid] = min(su[tid], su[tid + s]);
      __syncthreads();
    }
    tkey = su[0];
    __syncthreads();
  }
  const unsigned tstar = tkey;

  // pass 4: gumbel argmax over kept tokens (validated R5 code path)
  float best = -3.4e38f; int bidx = 0x7FFFFFFF;
  for (int i = tid; i < VV; i += 1024) {
    float zi = z[i];
    if (mono_key(zi) < tstar) continue;
    unsigned e = (unsigned)row * (unsigned)VV + (unsigned)i;
    unsigned bits = jax_random_bits(e);
    float f = __uint_as_float((bits >> 9) | 0x3F800000u) - 1.0f;
    float u = fmaxf(1.17549435082228750797e-38f, f);
    float g = -logf(-logf(u));
    float sc = zi + g;
    if (sc > best) { best = sc; bidx = i; }
  }
  sf[tid] = best; si[tid] = bidx; __syncthreads();
  for (int s = 512; s > 0; s >>= 1) {
    if (tid < s) {
      float ob = sf[tid + s]; int oi = si[tid + s];
      if (ob > sf[tid] || (ob == sf[tid] && oi < si[tid])) {
        sf[tid] = ob; si[tid] = oi;
      }
    }
    __syncthreads();
  }
  if (tid == 0) out[row] = si[0];
}

extern "C" void kernel_launch(void* const* d_in, const int* in_sizes, int n_in,
                              void* d_out, int out_size, void* d_ws, size_t ws_size,
                              hipStream_t stream) {
  const float* x = (const float*)d_in[0];
  const float* W = (const float*)d_in[1];
  const float* bias = (const float*)d_in[2];
  int* out = (int*)d_out;
  char* ws = (char*)d_ws;

  const size_t offXT = 0;                       // 524288 B
  const size_t offLog = 524288;                 // 12865792 B
  const size_t offPart = offLog + 12865792;     // sk * 12865792 B
  float* xT = (float*)(ws + offXT);
  float* logits = (float*)(ws + offLog);
  float* partial = (float*)(ws + offPart);

  int sk = 0;
  for (int c = 16; c >= 2; c >>= 1) {
    if (offPart + (size_t)c * 12865792 <= ws_size) { sk = c; break; }
  }

  transpose_kernel<<<(BB * DD + 255) / 256, 256, 0, stream>>>(x, xT);
  const int vblocks = (VV + 255) / 256;
  if (sk == 16) {
    dim3 g(vblocks, 16);
    gemm_splitk_lds_kernel<<<g, 256, 0, stream>>>(xT, W, partial);
    const size_t tot4 = (size_t)BB * VV / 4;
    reduce_bias_kernel<<<(unsigned)((tot4 + 255) / 256), 256, 0, stream>>>(
        partial, bias, logits, 16);
  } else if (sk) {
    dim3 g(vblocks, sk);
    gemm_splitk_kernel<<<g, 256, 0, stream>>>(xT, W, partial, DD / sk);
    const size_t tot4 = (size_t)BB * VV / 4;
    reduce_bias_kernel<<<(unsigned)((tot4 + 255) / 256), 256, 0, stream>>>(
        partial, bias, logits, sk);
  } else {
    gemm_kernel<<<vblocks, 256, 0, stream>>>(xT, W, bias, logits);
  }
  nucleus_sample_kernel<<<BB, 1024, 0, stream>>>(logits, out);
}

// Round 12
// 294.067 us; speedup vs baseline: 1.4180x; 1.4180x over previous
//
#include <hip/hip_runtime.h>
#include <hip/hip_bf16.h>
#include <stdint.h>

#define BB 64
#define DD 2048
#define VV 50257
#define NB 4096      // histogram bins
#define MAXC 2048    // boundary-bin collect capacity

typedef __attribute__((ext_vector_type(8))) short short8;
typedef __attribute__((ext_vector_type(4))) float f32x4;

struct U2 { unsigned x, y; };

__device__ __forceinline__ unsigned rotl32(unsigned v, int r) {
  return (v << r) | (v >> (32 - r));
}

// JAX threefry2x32 (jax/_src/prng.py lowering), 20 rounds.
__device__ __forceinline__ U2 threefry2x32(unsigned k0, unsigned k1,
                                           unsigned x0, unsigned x1) {
  unsigned k2 = k0 ^ k1 ^ 0x1BD11BDAu;
  x0 += k0; x1 += k1;
#define TF_R4(r1, r2, r3, r4)                         \
  x0 += x1; x1 = rotl32(x1, r1); x1 ^= x0;            \
  x0 += x1; x1 = rotl32(x1, r2); x1 ^= x0;            \
  x0 += x1; x1 = rotl32(x1, r3); x1 ^= x0;            \
  x0 += x1; x1 = rotl32(x1, r4); x1 ^= x0;
  TF_R4(13, 15, 26, 6)   x0 += k1; x1 += k2 + 1u;
  TF_R4(17, 29, 16, 24)  x0 += k2; x1 += k0 + 2u;
  TF_R4(13, 15, 26, 6)   x0 += k0; x1 += k1 + 3u;
  TF_R4(17, 29, 16, 24)  x0 += k1; x1 += k2 + 4u;
  TF_R4(13, 15, 26, 6)   x0 += k2; x1 += k0 + 5u;
#undef TF_R4
  U2 r; r.x = x0; r.y = x1; return r;
}

// VALIDATED (R5): partitionable threefry bits = XOR-fold of both cipher words,
// counter (hi=0, lo=e), key (0, 42).
__device__ __forceinline__ unsigned jax_random_bits(unsigned e) {
  U2 r = threefry2x32(0u, 42u, 0u, e);
  return r.x ^ r.y;
}

__device__ __forceinline__ unsigned mono_key(float zi) {
  unsigned bb = __float_as_uint(zi);
  return bb ^ ((bb >> 31) ? 0xFFFFFFFFu : 0x80000000u);
}

// bf16 round-to-nearest-even via bit ops (no dtype-library dependence).
__device__ __forceinline__ unsigned short f2bf(float f) {
  unsigned u = __float_as_uint(f);
  return (unsigned short)((u + 0x7FFFu + ((u >> 16) & 1u)) >> 16);
}
__device__ __forceinline__ float bf2f(unsigned short h) {
  return __uint_as_float(((unsigned)h) << 16);
}

// Pack x into MFMA-A-fragment-ready bf16 hi/lo arrays:
// pack index p = (d>>3)*64 + b holds ushort8 of x[b][8*(d>>3) .. +8).
// (A-frag for 16x16x32: lane holds 8 consecutive k -> one 16B load.)
__global__ __launch_bounds__(256) void pack_x_kernel(
    const float* __restrict__ x, unsigned short* __restrict__ xh,
    unsigned short* __restrict__ xl) {
  int i = blockIdx.x * 256 + threadIdx.x;     // 64 rows * 256 chunks
  if (i >= 64 * 256) return;
  int b = i >> 8;
  int c = i & 255;
  const float* xp = x + b * 2048 + c * 8;
  short8 hv, lv;
#pragma unroll
  for (int j = 0; j < 8; ++j) {
    float f = xp[j];
    unsigned short h = f2bf(f);
    hv[j] = (short)h;
    lv[j] = (short)f2bf(f - bf2f(h));
  }
  size_t p = ((size_t)c * 64 + b) * 8;
  *(short8*)(xh + p) = hv;
  *(short8*)(xl + p) = lv;
}

// MFMA GEMM, bf16-split (z = xh*Wh + xh*Wl + xl*Wh; xl*Wl ~2^-32 dropped).
// Block: 256 thr = 4 waves; wave w owns cols v0=blk*64+w*16; 4 row-tiles of 16
// cover all 64 rows. No split-K: 786 blocks, W streamed exactly once (412 MB).
// Layouts (16x16x32 bf16): A row=lane&15, k=(lane>>4)*8+j; B col=lane&15,
// same k; D col=lane&15, row=(lane>>4)*4+reg [m89-verified].
__global__ __launch_bounds__(256, 1) void gemm_mfma_kernel(
    const unsigned short* __restrict__ xh, const unsigned short* __restrict__ xl,
    const float* __restrict__ W, const float* __restrict__ bias,
    float* __restrict__ logits) {
  const int wave = threadIdx.x >> 6;
  const int lane = threadIdx.x & 63;
  const int lo = lane & 15, hi = lane >> 4;
  const int v0 = blockIdx.x * 64 + wave * 16;
  const int vcol = v0 + lo;
  const int vc = (vcol < VV) ? vcol : (VV - 1);

  f32x4 acc0 = {0.f, 0.f, 0.f, 0.f};
  f32x4 acc1 = {0.f, 0.f, 0.f, 0.f};
  f32x4 acc2 = {0.f, 0.f, 0.f, 0.f};
  f32x4 acc3 = {0.f, 0.f, 0.f, 0.f};

#pragma unroll 2
  for (int ks = 0; ks < 64; ++ks) {
    const int kbase = ks * 32 + hi * 8;
    const float* wp = W + (size_t)kbase * VV + vc;
    float wv[8];
#pragma unroll
    for (int j = 0; j < 8; ++j) wv[j] = wp[(size_t)j * VV];
    short8 bh, bl;
#pragma unroll
    for (int j = 0; j < 8; ++j) {
      unsigned short h = f2bf(wv[j]);
      bh[j] = (short)h;
      bl[j] = (short)f2bf(wv[j] - bf2f(h));
    }
    const int chunk = ks * 4 + hi;
#define DO_RT(ACC, RT)                                                      \
    {                                                                       \
      size_t p = ((size_t)chunk * 64 + (RT) * 16 + lo) * 8;                 \
      short8 ah = *(const short8*)(xh + p);                                 \
      short8 al = *(const short8*)(xl + p);                                 \
      ACC = __builtin_amdgcn_mfma_f32_16x16x32_bf16(ah, bh, ACC, 0, 0, 0);  \
      ACC = __builtin_amdgcn_mfma_f32_16x16x32_bf16(al, bh, ACC, 0, 0, 0);  \
      ACC = __builtin_amdgcn_mfma_f32_16x16x32_bf16(ah, bl, ACC, 0, 0, 0);  \
    }
    DO_RT(acc0, 0)
    DO_RT(acc1, 1)
    DO_RT(acc2, 2)
    DO_RT(acc3, 3)
#undef DO_RT
  }

  if (vcol < VV) {
    const float bv = bias[vcol];
#define ST_RT(ACC, RT)                                                      \
    {                                                                       \
      _Pragma("unroll")                                                     \
      for (int r = 0; r < 4; ++r) {                                         \
        int brow = (RT) * 16 + hi * 4 + r;                                  \
        logits[(size_t)brow * VV + vcol] = ACC[r] + bv;                     \
      }                                                                     \
    }
    ST_RT(acc0, 0)
    ST_RT(acc1, 1)
    ST_RT(acc2, 2)
    ST_RT(acc3, 3)
#undef ST_RT
  }
}

// Per row: max -> histogram of w=expf(z-m) binned by (m-z)*256 -> scan to find
// boundary bin (S_above <= C < S_above+bin) -> exact prefix sums within bin
// ((key desc, idx asc) order, same semantics as R5's validated binary search)
// -> t* = min kept key -> gumbel argmax over key >= t*. 4 logits passes vs 35.
__global__ __launch_bounds__(1024) void nucleus_sample_kernel(
    const float* __restrict__ logits, int* __restrict__ out) {
  __shared__ double sd[1024];
  __shared__ float sf[1024];
  __shared__ unsigned su[1024];
  __shared__ int si[1024];
  __shared__ double bins[NB];
  __shared__ int cidx[MAXC];
  __shared__ unsigned ckey[MAXC];
  __shared__ double cw[MAXC];
  __shared__ int ccount;
  __shared__ int sh_chunk;
  __shared__ int sh_bstar;
  __shared__ double sh_sabove;

  const int row = blockIdx.x;
  const int tid = threadIdx.x;
  const float* z = logits + (size_t)row * VV;

  for (int i = tid; i < NB; i += 1024) bins[i] = 0.0;
  if (tid == 0) { ccount = 0; sh_chunk = -1; sh_bstar = -1; }
  __syncthreads();

  // pass 1: row max
  float mx = -3.4e38f;
  for (int i = tid; i < VV; i += 1024) mx = fmaxf(mx, z[i]);
  sf[tid] = mx; __syncthreads();
  for (int s = 512; s > 0; s >>= 1) {
    if (tid < s) sf[tid] = fmaxf(sf[tid], sf[tid + s]);
    __syncthreads();
  }
  const float m = sf[0];
  __syncthreads();

  // pass 2: histogram
  for (int i = tid; i < VV; i += 1024) {
    float zi = z[i];
    int bin = (int)((m - zi) * 256.0f);
    bin = (bin < 0) ? 0 : ((bin > NB - 1) ? NB - 1 : bin);
    atomicAdd(&bins[bin], (double)expf(zi - m));
  }
  __syncthreads();

  // inclusive scan over 1024 chunk-sums (4 bins/chunk), f64
  {
    double c = bins[4 * tid] + bins[4 * tid + 1] + bins[4 * tid + 2] + bins[4 * tid + 3];
    sd[tid] = c; __syncthreads();
    for (int off = 1; off < 1024; off <<= 1) {
      double vv = (tid >= off) ? sd[tid - off] : 0.0;
      __syncthreads();
      sd[tid] += vv;
      __syncthreads();
    }
  }
  const double Z = sd[1023];
  const double C = (double)0.9f * Z;

  if (sd[tid] > C && (tid == 0 || sd[tid - 1] <= C)) sh_chunk = tid;
  __syncthreads();
  if (tid == 0) {
    int tc = sh_chunk;
    if (tc >= 0) {
      double run = (tc > 0) ? sd[tc - 1] : 0.0;
      for (int k = 0; k < 4; ++k) {
        double bw = bins[4 * tc + k];
        if (run + bw > C) { sh_bstar = 4 * tc + k; sh_sabove = run; break; }
        run += bw;
      }
    }
  }
  __syncthreads();
  const int bstar = sh_bstar;
  unsigned tkey = 0u;

  if (bstar >= 0) {
    const double Sab = sh_sabove;
    // pass 3: collect boundary-bin elements
    for (int i = tid; i < VV; i += 1024) {
      float zi = z[i];
      int bin = (int)((m - zi) * 256.0f);
      bin = (bin < 0) ? 0 : ((bin > NB - 1) ? NB - 1 : bin);
      if (bin == bstar) {
        int slot = atomicAdd(&ccount, 1);
        if (slot < MAXC) {
          ckey[slot] = mono_key(zi);
          cidx[slot] = i;
          cw[slot] = (double)expf(zi - m);
        }
      }
    }
    __syncthreads();
    int n = ccount; if (n > MAXC) n = MAXC;
    // kept iff exclusive prefix (in (key desc, idx asc) order) <= C
    unsigned mk = 0xFFFFFFFFu;
    for (int i = tid; i < n; i += 1024) {
      unsigned ki = ckey[i]; int ii = cidx[i];
      double T = Sab;
      for (int j = 0; j < n; ++j) {
        unsigned kj = ckey[j];
        if (kj > ki || (kj == ki && cidx[j] < ii)) T += cw[j];
      }
      if (T <= C) mk = (ki < mk) ? ki : mk;
    }
    su[tid] = mk; __syncthreads();
    for (int s = 512; s > 0; s >>= 1) {
      if (tid < s) su[tid] = min(su[tid], su[tid + s]);
      __syncthreads();
    }
    tkey = su[0];
    __syncthreads();
  }
  const unsigned tstar = tkey;

  // pass 4: gumbel argmax over kept tokens (validated R5 code path)
  float best = -3.4e38f; int bidx = 0x7FFFFFFF;
  for (int i = tid; i < VV; i += 1024) {
    float zi = z[i];
    if (mono_key(zi) < tstar) continue;
    unsigned e = (unsigned)row * (unsigned)VV + (unsigned)i;
    unsigned bits = jax_random_bits(e);
    float f = __uint_as_float((bits >> 9) | 0x3F800000u) - 1.0f;
    float u = fmaxf(1.17549435082228750797e-38f, f);
    float g = -logf(-logf(u));
    float sc = zi + g;
    if (sc > best) { best = sc; bidx = i; }
  }
  sf[tid] = best; si[tid] = bidx; __syncthreads();
  for (int s = 512; s > 0; s >>= 1) {
    if (tid < s) {
      float ob = sf[tid + s]; int oi = si[tid + s];
      if (ob > sf[tid] || (ob == sf[tid] && oi < si[tid])) {
        sf[tid] = ob; si[tid] = oi;
      }
    }
    __syncthreads();
  }
  if (tid == 0) out[row] = si[0];
}

extern "C" void kernel_launch(void* const* d_in, const int* in_sizes, int n_in,
                              void* d_out, int out_size, void* d_ws, size_t ws_size,
                              hipStream_t stream) {
  const float* x = (const float*)d_in[0];
  const float* W = (const float*)d_in[1];
  const float* bias = (const float*)d_in[2];
  int* out = (int*)d_out;
  char* ws = (char*)d_ws;

  unsigned short* xh = (unsigned short*)ws;              // 262144 B
  unsigned short* xl = (unsigned short*)(ws + 262144);   // 262144 B
  float* logits = (float*)(ws + 524288);                 // 12865792 B

  pack_x_kernel<<<64, 256, 0, stream>>>(x, xh, xl);
  const int vblocks = (VV + 63) / 64;   // 786
  gemm_mfma_kernel<<<vblocks, 256, 0, stream>>>(xh, xl, W, bias, logits);
  nucleus_sample_kernel<<<BB, 1024, 0, stream>>>(logits, out);
}

// Round 13
// 264.555 us; speedup vs baseline: 1.5762x; 1.1116x over previous
//
#include <hip/hip_runtime.h>
#include <hip/hip_bf16.h>
#include <stdint.h>

#define BB 64
#define DD 2048
#define VV 50257
#define NB 4096      // histogram bins
#define MAXC 2048    // boundary-bin collect capacity
#define QS 8         // gumbel-argmax blocks per row
#define QCH 6283     // ceil(VV/QS)

typedef __attribute__((ext_vector_type(8))) short short8;
typedef __attribute__((ext_vector_type(4))) float f32x4;

struct U2 { unsigned x, y; };

__device__ __forceinline__ unsigned rotl32(unsigned v, int r) {
  return (v << r) | (v >> (32 - r));
}

// JAX threefry2x32 (jax/_src/prng.py lowering), 20 rounds.
__device__ __forceinline__ U2 threefry2x32(unsigned k0, unsigned k1,
                                           unsigned x0, unsigned x1) {
  unsigned k2 = k0 ^ k1 ^ 0x1BD11BDAu;
  x0 += k0; x1 += k1;
#define TF_R4(r1, r2, r3, r4)                         \
  x0 += x1; x1 = rotl32(x1, r1); x1 ^= x0;            \
  x0 += x1; x1 = rotl32(x1, r2); x1 ^= x0;            \
  x0 += x1; x1 = rotl32(x1, r3); x1 ^= x0;            \
  x0 += x1; x1 = rotl32(x1, r4); x1 ^= x0;
  TF_R4(13, 15, 26, 6)   x0 += k1; x1 += k2 + 1u;
  TF_R4(17, 29, 16, 24)  x0 += k2; x1 += k0 + 2u;
  TF_R4(13, 15, 26, 6)   x0 += k0; x1 += k1 + 3u;
  TF_R4(17, 29, 16, 24)  x0 += k1; x1 += k2 + 4u;
  TF_R4(13, 15, 26, 6)   x0 += k2; x1 += k0 + 5u;
#undef TF_R4
  U2 r; r.x = x0; r.y = x1; return r;
}

// VALIDATED (R5): partitionable threefry bits = XOR-fold of both cipher words,
// counter (hi=0, lo=e), key (0, 42).
__device__ __forceinline__ unsigned jax_random_bits(unsigned e) {
  U2 r = threefry2x32(0u, 42u, 0u, e);
  return r.x ^ r.y;
}

__device__ __forceinline__ unsigned mono_key(float zi) {
  unsigned bb = __float_as_uint(zi);
  return bb ^ ((bb >> 31) ? 0xFFFFFFFFu : 0x80000000u);
}

// HW bf16 conversion (compiler fuses pairs into v_cvt_pk_bf16_f32 — m240:
// compiler-generated cvt is the fast form; R12's 5-op bit-math f2bf was ~90
// VALU/ks and throttled the gemm inner loop).
__device__ __forceinline__ unsigned short f2bf_hw(float f) {
  __hip_bfloat16 b = __float2bfloat16(f);
  unsigned short u;
  __builtin_memcpy(&u, &b, 2);
  return u;
}
__device__ __forceinline__ float bf2f(unsigned short h) {
  return __uint_as_float(((unsigned)h) << 16);
}

// Pack x into MFMA-A-fragment-ready bf16 hi/lo arrays:
// pack index p = (d>>3)*64 + b holds ushort8 of x[b][8*(d>>3) .. +8).
__global__ __launch_bounds__(256) void pack_x_kernel(
    const float* __restrict__ x, unsigned short* __restrict__ xh,
    unsigned short* __restrict__ xl) {
  int i = blockIdx.x * 256 + threadIdx.x;     // 64 rows * 256 chunks
  if (i >= 64 * 256) return;
  int b = i >> 8;
  int c = i & 255;
  const float* xp = x + b * 2048 + c * 8;
  short8 hv, lv;
#pragma unroll
  for (int j = 0; j < 8; ++j) {
    float f = xp[j];
    unsigned short h = f2bf_hw(f);
    hv[j] = (short)h;
    lv[j] = (short)f2bf_hw(f - bf2f(h));
  }
  size_t p = ((size_t)c * 64 + b) * 8;
  *(short8*)(xh + p) = hv;
  *(short8*)(xl + p) = lv;
}

// MFMA GEMM, bf16-split (z = xh*Wh + xh*Wl + xl*Wh; xl*Wl ~2^-32 dropped).
// Block: 256 thr = 4 waves; wave w owns cols v0=blk*64+w*16; 4 row-tiles of 16
// cover all 64 rows. No split-K: 786 blocks, W streamed exactly once (412 MB).
// Layouts (16x16x32 bf16): A row=lane&15, k=(lane>>4)*8+j; B col=lane&15,
// same k; D col=lane&15, row=(lane>>4)*4+reg [m89-verified, R12-validated].
__global__ __launch_bounds__(256, 1) void gemm_mfma_kernel(
    const unsigned short* __restrict__ xh, const unsigned short* __restrict__ xl,
    const float* __restrict__ W, const float* __restrict__ bias,
    float* __restrict__ logits) {
  const int wave = threadIdx.x >> 6;
  const int lane = threadIdx.x & 63;
  const int lo = lane & 15, hi = lane >> 4;
  const int v0 = blockIdx.x * 64 + wave * 16;
  const int vcol = v0 + lo;
  const int vc = (vcol < VV) ? vcol : (VV - 1);

  f32x4 acc0 = {0.f, 0.f, 0.f, 0.f};
  f32x4 acc1 = {0.f, 0.f, 0.f, 0.f};
  f32x4 acc2 = {0.f, 0.f, 0.f, 0.f};
  f32x4 acc3 = {0.f, 0.f, 0.f, 0.f};

#pragma unroll 2
  for (int ks = 0; ks < 64; ++ks) {
    const int kbase = ks * 32 + hi * 8;
    const float* wp = W + (size_t)kbase * VV + vc;
    float wv[8];
#pragma unroll
    for (int j = 0; j < 8; ++j) wv[j] = wp[(size_t)j * VV];
    short8 bh, bl;
#pragma unroll
    for (int j = 0; j < 8; ++j) {
      unsigned short h = f2bf_hw(wv[j]);
      bh[j] = (short)h;
      bl[j] = (short)f2bf_hw(wv[j] - bf2f(h));
    }
    const int chunk = ks * 4 + hi;
#define DO_RT(ACC, RT)                                                      \
    {                                                                       \
      size_t p = ((size_t)chunk * 64 + (RT) * 16 + lo) * 8;                 \
      short8 ah = *(const short8*)(xh + p);                                 \
      short8 al = *(const short8*)(xl + p);                                 \
      ACC = __builtin_amdgcn_mfma_f32_16x16x32_bf16(ah, bh, ACC, 0, 0, 0);  \
      ACC = __builtin_amdgcn_mfma_f32_16x16x32_bf16(al, bh, ACC, 0, 0, 0);  \
      ACC = __builtin_amdgcn_mfma_f32_16x16x32_bf16(ah, bl, ACC, 0, 0, 0);  \
    }
    DO_RT(acc0, 0)
    DO_RT(acc1, 1)
    DO_RT(acc2, 2)
    DO_RT(acc3, 3)
#undef DO_RT
  }

  if (vcol < VV) {
    const float bv = bias[vcol];
#define ST_RT(ACC, RT)                                                      \
    {                                                                       \
      _Pragma("unroll")                                                     \
      for (int r = 0; r < 4; ++r) {                                         \
        int brow = (RT) * 16 + hi * 4 + r;                                  \
        logits[(size_t)brow * VV + vcol] = ACC[r] + bv;                     \
      }                                                                     \
    }
    ST_RT(acc0, 0)
    ST_RT(acc1, 1)
    ST_RT(acc2, 2)
    ST_RT(acc3, 3)
#undef ST_RT
  }
}

// Per row: max -> histogram -> boundary-bin exact prefix sums -> tstar[row].
// (Gumbel argmax moved to its own 8-blocks/row kernel; this one was 25% GPU.)
__global__ __launch_bounds__(1024) void nucleus_tstar_kernel(
    const float* __restrict__ logits, unsigned* __restrict__ tstar_out,
    unsigned long long* __restrict__ pack) {
  __shared__ double sd[1024];
  __shared__ float sf[1024];
  __shared__ unsigned su[1024];
  __shared__ double bins[NB];
  __shared__ int cidx[MAXC];
  __shared__ unsigned ckey[MAXC];
  __shared__ double cw[MAXC];
  __shared__ int ccount;
  __shared__ int sh_chunk;
  __shared__ int sh_bstar;
  __shared__ double sh_sabove;

  const int row = blockIdx.x;
  const int tid = threadIdx.x;
  const float* z = logits + (size_t)row * VV;

  for (int i = tid; i < NB; i += 1024) bins[i] = 0.0;
  if (tid == 0) { ccount = 0; sh_chunk = -1; sh_bstar = -1; }
  __syncthreads();

  // pass 1: row max
  float mx = -3.4e38f;
  for (int i = tid; i < VV; i += 1024) mx = fmaxf(mx, z[i]);
  sf[tid] = mx; __syncthreads();
  for (int s = 512; s > 0; s >>= 1) {
    if (tid < s) sf[tid] = fmaxf(sf[tid], sf[tid + s]);
    __syncthreads();
  }
  const float m = sf[0];
  __syncthreads();

  // pass 2: histogram of exp(z-m) binned by (m-z)*256
  for (int i = tid; i < VV; i += 1024) {
    float zi = z[i];
    int bin = (int)((m - zi) * 256.0f);
    bin = (bin < 0) ? 0 : ((bin > NB - 1) ? NB - 1 : bin);
    atomicAdd(&bins[bin], (double)expf(zi - m));
  }
  __syncthreads();

  // inclusive scan over 1024 chunk-sums (4 bins/chunk), f64
  {
    double c = bins[4 * tid] + bins[4 * tid + 1] + bins[4 * tid + 2] + bins[4 * tid + 3];
    sd[tid] = c; __syncthreads();
    for (int off = 1; off < 1024; off <<= 1) {
      double vv = (tid >= off) ? sd[tid - off] : 0.0;
      __syncthreads();
      sd[tid] += vv;
      __syncthreads();
    }
  }
  const double Z = sd[1023];
  const double C = (double)0.9f * Z;

  if (sd[tid] > C && (tid == 0 || sd[tid - 1] <= C)) sh_chunk = tid;
  __syncthreads();
  if (tid == 0) {
    int tc = sh_chunk;
    if (tc >= 0) {
      double run = (tc > 0) ? sd[tc - 1] : 0.0;
      for (int k = 0; k < 4; ++k) {
        double bw = bins[4 * tc + k];
        if (run + bw > C) { sh_bstar = 4 * tc + k; sh_sabove = run; break; }
        run += bw;
      }
    }
  }
  __syncthreads();
  const int bstar = sh_bstar;
  unsigned tkey = 0u;

  if (bstar >= 0) {
    const double Sab = sh_sabove;
    // pass 3: collect boundary-bin elements
    for (int i = tid; i < VV; i += 1024) {
      float zi = z[i];
      int bin = (int)((m - zi) * 256.0f);
      bin = (bin < 0) ? 0 : ((bin > NB - 1) ? NB - 1 : bin);
      if (bin == bstar) {
        int slot = atomicAdd(&ccount, 1);
        if (slot < MAXC) {
          ckey[slot] = mono_key(zi);
          cidx[slot] = i;
          cw[slot] = (double)expf(zi - m);
        }
      }
    }
    __syncthreads();
    int n = ccount; if (n > MAXC) n = MAXC;
    // kept iff exclusive prefix (in (key desc, idx asc) order) <= C
    unsigned mk = 0xFFFFFFFFu;
    for (int i = tid; i < n; i += 1024) {
      unsigned ki = ckey[i]; int ii = cidx[i];
      double T = Sab;
      for (int j = 0; j < n; ++j) {
        unsigned kj = ckey[j];
        if (kj > ki || (kj == ki && cidx[j] < ii)) T += cw[j];
      }
      if (T <= C) mk = (ki < mk) ? ki : mk;
    }
    su[tid] = mk; __syncthreads();
    for (int s = 512; s > 0; s >>= 1) {
      if (tid < s) su[tid] = min(su[tid], su[tid + s]);
      __syncthreads();
    }
    tkey = su[0];
  }
  if (tid == 0) { tstar_out[row] = tkey; pack[row] = 0ull; }
}

// Gumbel argmax over kept tokens, 8 blocks/row; combine via atomicMax(u64)
// on pack = mono(best)<<32 | (~idx) — order-independent (deterministic) and
// reproduces (best desc, idx asc) tie-break exactly.
__global__ __launch_bounds__(1024) void gumbel_kernel(
    const float* __restrict__ logits, const unsigned* __restrict__ tstar_arr,
    unsigned long long* __restrict__ pack) {
  __shared__ float sf[1024];
  __shared__ int si[1024];
  const int row = blockIdx.x >> 3;
  const int q = blockIdx.x & 7;
  const int tid = threadIdx.x;
  const unsigned tstar = tstar_arr[row];
  const float* z = logits + (size_t)row * VV;
  const int i0 = q * QCH;
  const int i1 = (i0 + QCH < VV) ? (i0 + QCH) : VV;

  float best = -3.4e38f; int bidx = 0x7FFFFFFF;
  for (int i = i0 + tid; i < i1; i += 1024) {
    float zi = z[i];
    if (mono_key(zi) < tstar) continue;
    unsigned e = (unsigned)row * (unsigned)VV + (unsigned)i;
    unsigned bits = jax_random_bits(e);
    float f = __uint_as_float((bits >> 9) | 0x3F800000u) - 1.0f;
    float u = fmaxf(1.17549435082228750797e-38f, f);
    float g = -logf(-logf(u));
    float sc = zi + g;
    if (sc > best) { best = sc; bidx = i; }
  }
  sf[tid] = best; si[tid] = bidx; __syncthreads();
  for (int s = 512; s > 0; s >>= 1) {
    if (tid < s) {
      float ob = sf[tid + s]; int oi = si[tid + s];
      if (ob > sf[tid] || (ob == sf[tid] && oi < si[tid])) {
        sf[tid] = ob; si[tid] = oi;
      }
    }
    __syncthreads();
  }
  if (tid == 0 && si[0] != 0x7FFFFFFF) {
    unsigned long long p = ((unsigned long long)mono_key(sf[0]) << 32) |
                           (unsigned long long)(0xFFFFFFFFu - (unsigned)si[0]);
    atomicMax(pack + row, p);
  }
}

__global__ __launch_bounds__(64) void unpack_kernel(
    const unsigned long long* __restrict__ pack, int* __restrict__ out) {
  int r = threadIdx.x;
  if (r < BB) out[r] = (int)(0xFFFFFFFFu - (unsigned)(pack[r] & 0xFFFFFFFFull));
}

extern "C" void kernel_launch(void* const* d_in, const int* in_sizes, int n_in,
                              void* d_out, int out_size, void* d_ws, size_t ws_size,
                              hipStream_t stream) {
  const float* x = (const float*)d_in[0];
  const float* W = (const float*)d_in[1];
  const float* bias = (const float*)d_in[2];
  int* out = (int*)d_out;
  char* ws = (char*)d_ws;

  unsigned short* xh = (unsigned short*)ws;              // 262144 B
  unsigned short* xl = (unsigned short*)(ws + 262144);   // 262144 B
  float* logits = (float*)(ws + 524288);                 // 12865792 B
  unsigned* tstar = (unsigned*)(ws + 13390080);          // 256 B
  unsigned long long* pack = (unsigned long long*)(ws + 13390336);  // 512 B

  pack_x_kernel<<<64, 256, 0, stream>>>(x, xh, xl);
  const int vblocks = (VV + 63) / 64;   // 786
  gemm_mfma_kernel<<<vblocks, 256, 0, stream>>>(xh, xl, W, bias, logits);
  nucleus_tstar_kernel<<<BB, 1024, 0, stream>>>(logits, tstar, pack);
  gumbel_kernel<<<BB * QS, 1024, 0, stream>>>(logits, tstar, pack);
  unpack_kernel<<<1, 64, 0, stream>>>(pack, out);
}

// Round 14
// 246.333 us; speedup vs baseline: 1.6928x; 1.0740x over previous
//
#include <hip/hip_runtime.h>
#include <hip/hip_bf16.h>
#include <stdint.h>

#define BB 64
#define DD 2048
#define VV 50257
#define NB 4096      // histogram bins
#define MAXC 2048    // boundary-bin collect capacity
#define QS 8         // gumbel-argmax blocks per row
#define QCH 6283     // ceil(VV/QS)
#define SK 4         // MFMA split-K slices

typedef __attribute__((ext_vector_type(8))) short short8;
typedef __attribute__((ext_vector_type(4))) float f32x4;

struct U2 { unsigned x, y; };

__device__ __forceinline__ unsigned rotl32(unsigned v, int r) {
  return (v << r) | (v >> (32 - r));
}

// JAX threefry2x32 (jax/_src/prng.py lowering), 20 rounds.
__device__ __forceinline__ U2 threefry2x32(unsigned k0, unsigned k1,
                                           unsigned x0, unsigned x1) {
  unsigned k2 = k0 ^ k1 ^ 0x1BD11BDAu;
  x0 += k0; x1 += k1;
#define TF_R4(r1, r2, r3, r4)                         \
  x0 += x1; x1 = rotl32(x1, r1); x1 ^= x0;            \
  x0 += x1; x1 = rotl32(x1, r2); x1 ^= x0;            \
  x0 += x1; x1 = rotl32(x1, r3); x1 ^= x0;            \
  x0 += x1; x1 = rotl32(x1, r4); x1 ^= x0;
  TF_R4(13, 15, 26, 6)   x0 += k1; x1 += k2 + 1u;
  TF_R4(17, 29, 16, 24)  x0 += k2; x1 += k0 + 2u;
  TF_R4(13, 15, 26, 6)   x0 += k0; x1 += k1 + 3u;
  TF_R4(17, 29, 16, 24)  x0 += k1; x1 += k2 + 4u;
  TF_R4(13, 15, 26, 6)   x0 += k2; x1 += k0 + 5u;
#undef TF_R4
  U2 r; r.x = x0; r.y = x1; return r;
}

// VALIDATED (R5): partitionable threefry bits = XOR-fold of both cipher words,
// counter (hi=0, lo=e), key (0, 42).
__device__ __forceinline__ unsigned jax_random_bits(unsigned e) {
  U2 r = threefry2x32(0u, 42u, 0u, e);
  return r.x ^ r.y;
}

__device__ __forceinline__ unsigned mono_key(float zi) {
  unsigned bb = __float_as_uint(zi);
  return bb ^ ((bb >> 31) ? 0xFFFFFFFFu : 0x80000000u);
}

// HW bf16 conversion (R13-validated; compiler fuses into v_cvt_pk_bf16_f32).
__device__ __forceinline__ unsigned short f2bf_hw(float f) {
  __hip_bfloat16 b = __float2bfloat16(f);
  unsigned short u;
  __builtin_memcpy(&u, &b, 2);
  return u;
}
__device__ __forceinline__ float bf2f(unsigned short h) {
  return __uint_as_float(((unsigned)h) << 16);
}

// Pack x into MFMA-A-fragment-ready bf16 hi/lo arrays:
// pack index p = (d>>3)*64 + b holds ushort8 of x[b][8*(d>>3) .. +8).
__global__ __launch_bounds__(256) void pack_x_kernel(
    const float* __restrict__ x, unsigned short* __restrict__ xh,
    unsigned short* __restrict__ xl) {
  int i = blockIdx.x * 256 + threadIdx.x;     // 64 rows * 256 chunks
  if (i >= 64 * 256) return;
  int b = i >> 8;
  int c = i & 255;
  const float* xp = x + b * 2048 + c * 8;
  short8 hv, lv;
#pragma unroll
  for (int j = 0; j < 8; ++j) {
    float f = xp[j];
    unsigned short h = f2bf_hw(f);
    hv[j] = (short)h;
    lv[j] = (short)f2bf_hw(f - bf2f(h));
  }
  size_t p = ((size_t)c * 64 + b) * 8;
  *(short8*)(xh + p) = hv;
  *(short8*)(xl + p) = lv;
}

// MFMA GEMM, bf16-split, split-K=4. R13's kernel was grid-limited to
// 12 waves/CU (786 blocks); grid (786,4) -> 8 blocks/CU = 32 waves/CU (HW
// cap) for latency hiding of the ~900cyc scattered W loads. Inner loop
// byte-identical to R12/R13 (validated). Slice s covers ks [s*16, +16).
__global__ __launch_bounds__(256, 1) void gemm_mfma_kernel(
    const unsigned short* __restrict__ xh, const unsigned short* __restrict__ xl,
    const float* __restrict__ W, float* __restrict__ partial) {
  const int wave = threadIdx.x >> 6;
  const int lane = threadIdx.x & 63;
  const int lo = lane & 15, hi = lane >> 4;
  const int v0 = blockIdx.x * 64 + wave * 16;
  const int vcol = v0 + lo;
  const int vc = (vcol < VV) ? vcol : (VV - 1);
  const int ks0 = blockIdx.y * 16;

  f32x4 acc0 = {0.f, 0.f, 0.f, 0.f};
  f32x4 acc1 = {0.f, 0.f, 0.f, 0.f};
  f32x4 acc2 = {0.f, 0.f, 0.f, 0.f};
  f32x4 acc3 = {0.f, 0.f, 0.f, 0.f};

#pragma unroll 2
  for (int kss = 0; kss < 16; ++kss) {
    const int ks = ks0 + kss;
    const int kbase = ks * 32 + hi * 8;
    const float* wp = W + (size_t)kbase * VV + vc;
    float wv[8];
#pragma unroll
    for (int j = 0; j < 8; ++j) wv[j] = wp[(size_t)j * VV];
    short8 bh, bl;
#pragma unroll
    for (int j = 0; j < 8; ++j) {
      unsigned short h = f2bf_hw(wv[j]);
      bh[j] = (short)h;
      bl[j] = (short)f2bf_hw(wv[j] - bf2f(h));
    }
    const int chunk = ks * 4 + hi;
#define DO_RT(ACC, RT)                                                      \
    {                                                                       \
      size_t p = ((size_t)chunk * 64 + (RT) * 16 + lo) * 8;                 \
      short8 ah = *(const short8*)(xh + p);                                 \
      short8 al = *(const short8*)(xl + p);                                 \
      ACC = __builtin_amdgcn_mfma_f32_16x16x32_bf16(ah, bh, ACC, 0, 0, 0);  \
      ACC = __builtin_amdgcn_mfma_f32_16x16x32_bf16(al, bh, ACC, 0, 0, 0);  \
      ACC = __builtin_amdgcn_mfma_f32_16x16x32_bf16(ah, bl, ACC, 0, 0, 0);  \
    }
    DO_RT(acc0, 0)
    DO_RT(acc1, 1)
    DO_RT(acc2, 2)
    DO_RT(acc3, 3)
#undef DO_RT
  }

  if (vcol < VV) {
    float* pp = partial + (size_t)blockIdx.y * BB * VV;
#define ST_RT(ACC, RT)                                                      \
    {                                                                       \
      _Pragma("unroll")                                                     \
      for (int r = 0; r < 4; ++r) {                                         \
        int brow = (RT) * 16 + hi * 4 + r;                                  \
        pp[(size_t)brow * VV + vcol] = ACC[r];                              \
      }                                                                     \
    }
    ST_RT(acc0, 0)
    ST_RT(acc1, 1)
    ST_RT(acc2, 2)
    ST_RT(acc3, 3)
#undef ST_RT
  }
}

// float4 flat reduce + bias (validated R7-R10 shape): planes [s][flat].
__global__ __launch_bounds__(256) void reduce_bias_kernel(
    const float* __restrict__ partial, const float* __restrict__ bias,
    float* __restrict__ logits) {
  const size_t tot4 = (size_t)BB * VV / 4;   // 804112
  size_t i = (size_t)blockIdx.x * 256 + threadIdx.x;
  if (i >= tot4) return;
  float4 acc;
  {
    size_t f = i * 4;
    int v0 = (int)(f % VV);
    acc.x = bias[v0];
    acc.y = bias[(v0 + 1 == VV) ? 0 : v0 + 1];
    acc.z = bias[(v0 + 1 >= VV) ? (v0 + 2 - VV) : v0 + 2];
    acc.w = bias[(v0 + 2 >= VV) ? (v0 + 3 - VV) : v0 + 3];
  }
#pragma unroll
  for (int s = 0; s < SK; ++s) {
    float4 p = ((const float4*)(partial + (size_t)s * BB * VV))[i];
    acc.x += p.x; acc.y += p.y; acc.z += p.z; acc.w += p.w;
  }
  ((float4*)logits)[i] = acc;
}

// Per row: max -> histogram -> boundary-bin exact prefix sums -> tstar[row].
__global__ __launch_bounds__(1024) void nucleus_tstar_kernel(
    const float* __restrict__ logits, unsigned* __restrict__ tstar_out,
    unsigned long long* __restrict__ pack) {
  __shared__ double sd[1024];
  __shared__ float sf[1024];
  __shared__ unsigned su[1024];
  __shared__ double bins[NB];
  __shared__ int cidx[MAXC];
  __shared__ unsigned ckey[MAXC];
  __shared__ double cw[MAXC];
  __shared__ int ccount;
  __shared__ int sh_chunk;
  __shared__ int sh_bstar;
  __shared__ double sh_sabove;

  const int row = blockIdx.x;
  const int tid = threadIdx.x;
  const float* z = logits + (size_t)row * VV;

  for (int i = tid; i < NB; i += 1024) bins[i] = 0.0;
  if (tid == 0) { ccount = 0; sh_chunk = -1; sh_bstar = -1; }
  __syncthreads();

  // pass 1: row max
  float mx = -3.4e38f;
  for (int i = tid; i < VV; i += 1024) mx = fmaxf(mx, z[i]);
  sf[tid] = mx; __syncthreads();
  for (int s = 512; s > 0; s >>= 1) {
    if (tid < s) sf[tid] = fmaxf(sf[tid], sf[tid + s]);
    __syncthreads();
  }
  const float m = sf[0];
  __syncthreads();

  // pass 2: histogram of exp(z-m) binned by (m-z)*256
  for (int i = tid; i < VV; i += 1024) {
    float zi = z[i];
    int bin = (int)((m - zi) * 256.0f);
    bin = (bin < 0) ? 0 : ((bin > NB - 1) ? NB - 1 : bin);
    atomicAdd(&bins[bin], (double)expf(zi - m));
  }
  __syncthreads();

  // inclusive scan over 1024 chunk-sums (4 bins/chunk), f64
  {
    double c = bins[4 * tid] + bins[4 * tid + 1] + bins[4 * tid + 2] + bins[4 * tid + 3];
    sd[tid] = c; __syncthreads();
    for (int off = 1; off < 1024; off <<= 1) {
      double vv = (tid >= off) ? sd[tid - off] : 0.0;
      __syncthreads();
      sd[tid] += vv;
      __syncthreads();
    }
  }
  const double Z = sd[1023];
  const double C = (double)0.9f * Z;

  if (sd[tid] > C && (tid == 0 || sd[tid - 1] <= C)) sh_chunk = tid;
  __syncthreads();
  if (tid == 0) {
    int tc = sh_chunk;
    if (tc >= 0) {
      double run = (tc > 0) ? sd[tc - 1] : 0.0;
      for (int k = 0; k < 4; ++k) {
        double bw = bins[4 * tc + k];
        if (run + bw > C) { sh_bstar = 4 * tc + k; sh_sabove = run; break; }
        run += bw;
      }
    }
  }
  __syncthreads();
  const int bstar = sh_bstar;
  unsigned tkey = 0u;

  if (bstar >= 0) {
    const double Sab = sh_sabove;
    // pass 3: collect boundary-bin elements
    for (int i = tid; i < VV; i += 1024) {
      float zi = z[i];
      int bin = (int)((m - zi) * 256.0f);
      bin = (bin < 0) ? 0 : ((bin > NB - 1) ? NB - 1 : bin);
      if (bin == bstar) {
        int slot = atomicAdd(&ccount, 1);
        if (slot < MAXC) {
          ckey[slot] = mono_key(zi);
          cidx[slot] = i;
          cw[slot] = (double)expf(zi - m);
        }
      }
    }
    __syncthreads();
    int n = ccount; if (n > MAXC) n = MAXC;
    // kept iff exclusive prefix (in (key desc, idx asc) order) <= C
    unsigned mk = 0xFFFFFFFFu;
    for (int i = tid; i < n; i += 1024) {
      unsigned ki = ckey[i]; int ii = cidx[i];
      double T = Sab;
      for (int j = 0; j < n; ++j) {
        unsigned kj = ckey[j];
        if (kj > ki || (kj == ki && cidx[j] < ii)) T += cw[j];
      }
      if (T <= C) mk = (ki < mk) ? ki : mk;
    }
    su[tid] = mk; __syncthreads();
    for (int s = 512; s > 0; s >>= 1) {
      if (tid < s) su[tid] = min(su[tid], su[tid + s]);
      __syncthreads();
    }
    tkey = su[0];
  }
  if (tid == 0) { tstar_out[row] = tkey; pack[row] = 0ull; }
}

// Gumbel argmax over kept tokens, 8 blocks/row; combine via atomicMax(u64)
// on pack = mono(best)<<32 | (~idx) — order-independent (deterministic) and
// reproduces (best desc, idx asc) tie-break exactly.
__global__ __launch_bounds__(1024) void gumbel_kernel(
    const float* __restrict__ logits, const unsigned* __restrict__ tstar_arr,
    unsigned long long* __restrict__ pack) {
  __shared__ float sf[1024];
  __shared__ int si[1024];
  const int row = blockIdx.x >> 3;
  const int q = blockIdx.x & 7;
  const int tid = threadIdx.x;
  const unsigned tstar = tstar_arr[row];
  const float* z = logits + (size_t)row * VV;
  const int i0 = q * QCH;
  const int i1 = (i0 + QCH < VV) ? (i0 + QCH) : VV;

  float best = -3.4e38f; int bidx = 0x7FFFFFFF;
  for (int i = i0 + tid; i < i1; i += 1024) {
    float zi = z[i];
    if (mono_key(zi) < tstar) continue;
    unsigned e = (unsigned)row * (unsigned)VV + (unsigned)i;
    unsigned bits = jax_random_bits(e);
    float f = __uint_as_float((bits >> 9) | 0x3F800000u) - 1.0f;
    float u = fmaxf(1.17549435082228750797e-38f, f);
    float g = -logf(-logf(u));
    float sc = zi + g;
    if (sc > best) { best = sc; bidx = i; }
  }
  sf[tid] = best; si[tid] = bidx; __syncthreads();
  for (int s = 512; s > 0; s >>= 1) {
    if (tid < s) {
      float ob = sf[tid + s]; int oi = si[tid + s];
      if (ob > sf[tid] || (ob == sf[tid] && oi < si[tid])) {
        sf[tid] = ob; si[tid] = oi;
      }
    }
    __syncthreads();
  }
  if (tid == 0 && si[0] != 0x7FFFFFFF) {
    unsigned long long p = ((unsigned long long)mono_key(sf[0]) << 32) |
                           (unsigned long long)(0xFFFFFFFFu - (unsigned)si[0]);
    atomicMax(pack + row, p);
  }
}

__global__ __launch_bounds__(64) void unpack_kernel(
    const unsigned long long* __restrict__ pack, int* __restrict__ out) {
  int r = threadIdx.x;
  if (r < BB) out[r] = (int)(0xFFFFFFFFu - (unsigned)(pack[r] & 0xFFFFFFFFull));
}

extern "C" void kernel_launch(void* const* d_in, const int* in_sizes, int n_in,
                              void* d_out, int out_size, void* d_ws, size_t ws_size,
                              hipStream_t stream) {
  const float* x = (const float*)d_in[0];
  const float* W = (const float*)d_in[1];
  const float* bias = (const float*)d_in[2];
  int* out = (int*)d_out;
  char* ws = (char*)d_ws;

  unsigned short* xh = (unsigned short*)ws;              // 262144 B
  unsigned short* xl = (unsigned short*)(ws + 262144);   // 262144 B
  float* logits = (float*)(ws + 524288);                 // 12865792 B
  float* partial = (float*)(ws + 13390080);              // 4*12865792 B
  unsigned* tstar = (unsigned*)(ws + 64853248);          // 256 B
  unsigned long long* pack = (unsigned long long*)(ws + 64853504);  // 512 B

  pack_x_kernel<<<64, 256, 0, stream>>>(x, xh, xl);
  const int vblocks = (VV + 63) / 64;   // 786
  dim3 g(vblocks, SK);
  gemm_mfma_kernel<<<g, 256, 0, stream>>>(xh, xl, W, partial);
  const size_t tot4 = (size_t)BB * VV / 4;
  reduce_bias_kernel<<<(unsigned)((tot4 + 255) / 256), 256, 0, stream>>>(
      partial, bias, logits);
  nucleus_tstar_kernel<<<BB, 1024, 0, stream>>>(logits, tstar, pack);
  gumbel_kernel<<<BB * QS, 1024, 0, stream>>>(logits, tstar, pack);
  unpack_kernel<<<1, 64, 0, stream>>>(pack, out);
}